// Round 1
// baseline (9420.409 us; speedup 1.0000x reference)
//
#include <hip/hip_runtime.h>

#define B_IMG 512
#define C1OFF (-1.2432432432432432f)

__device__ __forceinline__ float relu_(float v) { return v > 0.f ? v : 0.f; }

__device__ __forceinline__ void loadrow12(const float* __restrict__ p, float r[12]) {
    float4 a = *(const float4*)(p);
    float4 b = *(const float4*)(p + 4);
    float4 c = *(const float4*)(p + 8);
    r[0]=a.x; r[1]=a.y; r[2]=a.z;  r[3]=a.w;
    r[4]=b.x; r[5]=b.y; r[6]=b.z;  r[7]=b.w;
    r[8]=c.x; r[9]=c.y; r[10]=c.z; r[11]=c.w;
}

// One 9-wide weight row applied to two input rows (2x4 output patch).
#define CSTEP(TOP, BOT, KY)                                               \
    do {                                                                  \
        loadrow12(bp + ((KY) + 1) * IW, (BOT));                           \
        const float* wr = wb + (KY) * 9;                                  \
        _Pragma("unroll")                                                 \
        for (int kx = 0; kx < 9; ++kx) {                                  \
            float w = wr[kx];                                             \
            _Pragma("unroll")                                             \
            for (int j = 0; j < 4; ++j) {                                 \
                acc0[j] = fmaf(w, (TOP)[kx + j], acc0[j]);                \
                acc1[j] = fmaf(w, (BOT)[kx + j], acc1[j]);                \
            }                                                             \
        }                                                                 \
    } while (0)

// ---------------- FC: h = relu(x @ W^T + b), M=512 K=3600 N=3600 -------------
__global__ __launch_bounds__(256) void fc_kernel(
    const float* __restrict__ X, const float* __restrict__ W,
    const float* __restrict__ Bv, float* __restrict__ H)
{
    __shared__ __align__(16) float As[16][68];
    __shared__ __align__(16) float Bs[16][68];
    const int tid = threadIdx.x;
    const int m0 = blockIdx.y * 64;
    const int n0 = blockIdx.x * 64;
    const int tm = tid >> 4, tn = tid & 15;
    const int lr = tid >> 2;            // 0..63
    const int lk = (tid & 3) << 2;      // 0,4,8,12
    const bool bvalid = (n0 + lr) < 3600;
    const float* Arow = X + (size_t)(m0 + lr) * 3600 + lk;
    const float* Brow = W + (size_t)(bvalid ? (n0 + lr) : 0) * 3600 + lk;
    float acc[4][4] = {};
    for (int k0 = 0; k0 < 3600; k0 += 16) {
        float4 av = *(const float4*)(Arow + k0);
        float4 bv = make_float4(0.f, 0.f, 0.f, 0.f);
        if (bvalid) bv = *(const float4*)(Brow + k0);
        __syncthreads();
        As[lk + 0][lr] = av.x; As[lk + 1][lr] = av.y;
        As[lk + 2][lr] = av.z; As[lk + 3][lr] = av.w;
        Bs[lk + 0][lr] = bv.x; Bs[lk + 1][lr] = bv.y;
        Bs[lk + 2][lr] = bv.z; Bs[lk + 3][lr] = bv.w;
        __syncthreads();
        #pragma unroll
        for (int kk = 0; kk < 16; ++kk) {
            float a[4], b[4];
            *(float4*)a = *(const float4*)&As[kk][tm << 2];
            *(float4*)b = *(const float4*)&Bs[kk][tn << 2];
            #pragma unroll
            for (int i = 0; i < 4; ++i)
                #pragma unroll
                for (int j = 0; j < 4; ++j)
                    acc[i][j] = fmaf(a[i], b[j], acc[i][j]);
        }
    }
    #pragma unroll
    for (int i = 0; i < 4; ++i) {
        int m = m0 + (tm << 2) + i;
        #pragma unroll
        for (int j = 0; j < 4; ++j) {
            int n = n0 + (tn << 2) + j;
            if (n < 3600) {
                float v = acc[i][j] + Bv[n];
                H[(size_t)m * 3600 + n] = relu_(v);
            }
        }
    }
}

// ---------------- padding formula (build_padded fused) -----------------------
__device__ __forceinline__ float pad_core(const float* __restrict__ xb,
                                          const float* __restrict__ hb,
                                          int ch, int r, int c)
{
    if (r < 16) return 0.f;                 // top zero (cols >= 16 path)
    int rr = (r <= 75) ? r : (151 - r);     // bottom mirror
    int cc = (c <= 75) ? c : (151 - c);     // right mirror
    int i = rr - 16, j = cc - 16;
    if (ch == 0) return xb[i * 60 + j];
    if (ch == 1) return hb[i * 60 + j];
    return (j >= 51) ? 1.0f : ((j >= 41) ? 0.5f : 0.0f);   // ff channel
}

__device__ __forceinline__ float pad_val(const float* __restrict__ xb,
                                         const float* __restrict__ hb,
                                         int ch, int r, int c)
{
    if (c >= 16) return pad_core(xb, hb, ch, r, c);
    float v = pad_core(xb, hb, ch, r, 31 - c);   // left mirror across col 16
    return (ch == 1) ? (C1OFF - v) : v;
}

// ---------------- conv1: virtual-padded (3,92,92) -> (8,84,84), relu ---------
__global__ __launch_bounds__(512) void conv1_kernel(
    const float* __restrict__ x, const float* __restrict__ h,
    const float* __restrict__ wt, const float* __restrict__ bias,
    float* __restrict__ out)
{
    __shared__ __align__(16) float pim[3 * 92 * 92];
    __shared__ __align__(16) float ws[8 * 3 * 81];
    const int tid = threadIdx.x;
    const int b = blockIdx.x;
    for (int i = tid; i < (8 * 3 * 81) / 4; i += 512)
        *(float4*)&ws[i * 4] = *(const float4*)&wt[i * 4];
    const float* xb = x + (size_t)b * 3600;
    const float* hb = h + (size_t)b * 3600;
    for (int i = tid; i < 3 * 92 * 92; i += 512) {
        int ch = i / 8464;
        int rem = i - ch * 8464;
        int r = rem / 92;
        int c = rem - r * 92;
        pim[i] = pad_val(xb, hb, ch, r, c);
    }
    __syncthreads();
    constexpr int IW = 92, OW = 84, NGX = 21, NGY = 42, OC = 8, IC = 3;
    for (int g = tid; g < OC * NGY * NGX; g += 512) {
        int oc = g / (NGY * NGX);
        int rem = g - oc * (NGY * NGX);
        int gy = rem / NGX;
        int oy = gy * 2;
        int x0 = (rem - gy * NGX) * 4;
        float bvl = bias[oc];
        float acc0[4] = {bvl, bvl, bvl, bvl}, acc1[4] = {bvl, bvl, bvl, bvl};
        for (int ic = 0; ic < IC; ++ic) {
            const float* bp = &pim[ic * 8464 + oy * IW + x0];
            const float* wb = &ws[(oc * IC + ic) * 81];
            float r0[12], r1[12];
            loadrow12(bp, r0);
            CSTEP(r0, r1, 0); CSTEP(r1, r0, 1); CSTEP(r0, r1, 2);
            CSTEP(r1, r0, 3); CSTEP(r0, r1, 4); CSTEP(r1, r0, 5);
            CSTEP(r0, r1, 6); CSTEP(r1, r0, 7); CSTEP(r0, r1, 8);
        }
        size_t ob = ((size_t)b * OC + oc) * (OW * OW) + (size_t)oy * OW + x0;
        float4 v0 = make_float4(relu_(acc0[0]), relu_(acc0[1]), relu_(acc0[2]), relu_(acc0[3]));
        float4 v1 = make_float4(relu_(acc1[0]), relu_(acc1[1]), relu_(acc1[2]), relu_(acc1[3]));
        *(float4*)&out[ob] = v0;
        *(float4*)&out[ob + OW] = v1;
    }
}

// ---------------- generic valid 9x9 conv, LDS-staged row strips --------------
template<int IC, int OC, int IH, int SR, int NSTRIP, int NT, bool RELU>
__global__ __launch_bounds__(NT) void conv9(
    const float* __restrict__ in, const float* __restrict__ wt,
    const float* __restrict__ bias, float* __restrict__ out)
{
    constexpr int IW = IH;
    constexpr int OW = IW - 8;
    constexpr int SROWS = SR + 8;
    __shared__ __align__(16) float ins[IC * SROWS * IW];
    __shared__ __align__(16) float ws[OC * IC * 81];
    const int tid = threadIdx.x;
    const int b = blockIdx.x / NSTRIP;
    const int strip = blockIdx.x % NSTRIP;
    const int y0 = strip * SR;
    for (int i = tid; i < (OC * IC * 81) / 4; i += NT)
        *(float4*)&ws[i * 4] = *(const float4*)&wt[i * 4];
    const size_t ibase = (size_t)b * IC * IH * IW + (size_t)y0 * IW;
    constexpr int CPY = IC * SROWS * IW / 4;
    for (int i = tid; i < CPY; i += NT) {
        int idx = i * 4;
        int ic = idx / (SROWS * IW);
        int rem = idx - ic * (SROWS * IW);
        *(float4*)&ins[idx] = *(const float4*)&in[ibase + (size_t)ic * IH * IW + rem];
    }
    __syncthreads();
    constexpr int NGX = OW / 4;
    constexpr int NGY = SR / 2;
    for (int g = tid; g < OC * NGY * NGX; g += NT) {
        int oc = g / (NGY * NGX);
        int rem = g - oc * (NGY * NGX);
        int gy = rem / NGX;
        int oy = gy * 2;
        int x0 = (rem - gy * NGX) * 4;
        float bvl = bias[oc];
        float acc0[4] = {bvl, bvl, bvl, bvl}, acc1[4] = {bvl, bvl, bvl, bvl};
        for (int ic = 0; ic < IC; ++ic) {
            const float* bp = &ins[(ic * SROWS + oy) * IW + x0];
            const float* wb = &ws[(oc * IC + ic) * 81];
            float r0[12], r1[12];
            loadrow12(bp, r0);
            CSTEP(r0, r1, 0); CSTEP(r1, r0, 1); CSTEP(r0, r1, 2);
            CSTEP(r1, r0, 3); CSTEP(r0, r1, 4); CSTEP(r1, r0, 5);
            CSTEP(r0, r1, 6); CSTEP(r1, r0, 7); CSTEP(r0, r1, 8);
        }
        size_t ob = ((size_t)b * OC + oc) * (OW * OW) + (size_t)(y0 + oy) * OW + x0;
        float4 v0, v1;
        if (RELU) {
            v0 = make_float4(relu_(acc0[0]), relu_(acc0[1]), relu_(acc0[2]), relu_(acc0[3]));
            v1 = make_float4(relu_(acc1[0]), relu_(acc1[1]), relu_(acc1[2]), relu_(acc1[3]));
        } else {
            v0 = make_float4(acc0[0], acc0[1], acc0[2], acc0[3]);
            v1 = make_float4(acc1[0], acc1[1], acc1[2], acc1[3]);
        }
        *(float4*)&out[ob] = v0;
        *(float4*)&out[ob + OW] = v1;
    }
}

extern "C" void kernel_launch(void* const* d_in, const int* in_sizes, int n_in,
                              void* d_out, int out_size, void* d_ws, size_t ws_size,
                              hipStream_t stream)
{
    const float* x   = (const float*)d_in[0];
    const float* fcw = (const float*)d_in[1];
    const float* fcb = (const float*)d_in[2];
    const float* w1  = (const float*)d_in[3];
    const float* b1  = (const float*)d_in[4];
    const float* w2  = (const float*)d_in[5];
    const float* b2  = (const float*)d_in[6];
    const float* w3  = (const float*)d_in[7];
    const float* b3  = (const float*)d_in[8];
    const float* w4  = (const float*)d_in[9];
    const float* b4  = (const float*)d_in[10];

    float* h  = (float*)d_out;      // h lives in d_out (same size: 512*3600)
    float* t1 = (float*)d_ws;       // conv1 out (8*84*84/img), also conv3 out

    // chunk images if workspace is small: need (t1 + t2) per image
    size_t per_img = (size_t)(8 * 84 * 84 + 8 * 76 * 76) * sizeof(float);
    int CH = (int)(ws_size / per_img);
    if (CH > B_IMG) CH = B_IMG;
    if (CH < 1) CH = 1;
    float* t2 = t1 + (size_t)CH * (8 * 84 * 84);

    fc_kernel<<<dim3(57, 8), 256, 0, stream>>>(x, fcw, fcb, h);

    for (int it = 0; it < 5; ++it) {
        for (int c0 = 0; c0 < B_IMG; c0 += CH) {
            int cn = (B_IMG - c0) < CH ? (B_IMG - c0) : CH;
            conv1_kernel<<<cn, 512, 0, stream>>>(
                x + (size_t)c0 * 3600, h + (size_t)c0 * 3600, w1, b1, t1);
            conv9<8, 8, 84, 38, 2, 512, true><<<cn * 2, 512, 0, stream>>>(t1, w2, b2, t2);
            conv9<8, 8, 76, 34, 2, 512, true><<<cn * 2, 512, 0, stream>>>(t2, w3, b3, t1);
            conv9<8, 1, 68, 30, 2, 256, false><<<cn * 2, 256, 0, stream>>>(
                t1, w4, b4, h + (size_t)c0 * 3600);
        }
    }
}